// Round 7
// baseline (62.726 us; speedup 1.0000x reference)
//
#include <hip/hip_runtime.h>
#include <climits>

// Problem constants (fixed by the reference's setup_inputs()):
#define BATCH   8
#define TFRAMES 8
#define BT      (BATCH * TFRAMES)   // 64
#define NPTS    1024
#define NCH     32
#define WS      128
#define HW      (WS * WS)           // 16384
#define CELLS   64                  // cells per chunk (tile kernel)
#define CHUNKS  (HW / CELLS)        // 256
#define CPAD    33                  // padded channel stride in LDS
#define TPB     256

// ---------------------------------------------------------------------------
// Kernel A: per-frame scan -> packed entries, per-chunk ranges, AND segof[p]
// (segment id of each sorted position, built by LDS scatter).
// 64 blocks x 256 threads.
// ---------------------------------------------------------------------------
__global__ __launch_bounds__(256) void scan_kernel(
    const int* __restrict__ uniq_cnt,    // [BT][NPTS]
    const int* __restrict__ uniq_list,   // [BT][NPTS]
    int4*      __restrict__ entries,     // [BT][NPTS] {cell,cnt,start,0}
    int*       __restrict__ ranges,      // [BT][CHUNKS+1]
    int*       __restrict__ segof)       // [BT][NPTS]
{
    __shared__ int s_key[NPTS];
    __shared__ int s_segof[NPTS];
    __shared__ int s_wsum[4];

    const int tid  = threadIdx.x;
    const int bt   = blockIdx.x;
    const int wave = tid >> 6;
    const int lane = tid & 63;

    const int4 c4 = reinterpret_cast<const int4*>(uniq_cnt + bt * NPTS)[tid];
    const int4 l4 = reinterpret_cast<const int4*>(uniq_list + bt * NPTS)[tid];
    s_key[tid * 4 + 0] = (c4.x > 0) ? l4.x : INT_MAX;
    s_key[tid * 4 + 1] = (c4.y > 0) ? l4.y : INT_MAX;
    s_key[tid * 4 + 2] = (c4.z > 0) ? l4.z : INT_MAX;
    s_key[tid * 4 + 3] = (c4.w > 0) ? l4.w : INT_MAX;

    const int lsum = c4.x + c4.y + c4.z + c4.w;

    int inc = lsum;
#pragma unroll
    for (int d = 1; d < 64; d <<= 1) {
        const int v = __shfl_up(inc, d);
        if (lane >= d) inc += v;
    }
    if (lane == 63) s_wsum[wave] = inc;
    __syncthreads();

    int woff = 0;
#pragma unroll
    for (int w = 0; w < 4; ++w)
        if (w < wave) woff += s_wsum[w];

    int st = woff + inc - lsum;   // exclusive prefix for this thread's 4 slots
    const int e_base = tid * 4;
    int4* ep = entries + (size_t)bt * NPTS + e_base;

    ep[0] = make_int4(l4.x, c4.x, st, 0);
    for (int q = 0; q < c4.x; ++q) s_segof[st + q] = e_base + 0;
    st += c4.x;
    ep[1] = make_int4(l4.y, c4.y, st, 0);
    for (int q = 0; q < c4.y; ++q) s_segof[st + q] = e_base + 1;
    st += c4.y;
    ep[2] = make_int4(l4.z, c4.z, st, 0);
    for (int q = 0; q < c4.z; ++q) s_segof[st + q] = e_base + 2;
    st += c4.z;
    ep[3] = make_int4(l4.w, c4.w, st, 0);
    for (int q = 0; q < c4.w; ++q) s_segof[st + q] = e_base + 3;

    __syncthreads();

    // coalesced segof dump
    reinterpret_cast<int4*>(segof + bt * NPTS)[tid] =
        *reinterpret_cast<int4*>(&s_segof[tid * 4]);

    // per-chunk boundary searches over LDS keys
    for (int k = tid; k <= CHUNKS; k += 256) {
        const int X = k * CELLS;
        int lo = 0, hi = NPTS;
        while (lo < hi) {
            const int mid = (lo + hi) >> 1;
            if (s_key[mid] < X) lo = mid + 1; else hi = mid;
        }
        ranges[bt * (CHUNKS + 1) + k] = lo;
    }
}

// ---------------------------------------------------------------------------
// Kernel B: point-parallel segment means. Block = (frame, quarter of 1024
// sorted positions). si/segof are pure streams; w rows are 1-deep gathers
// with 32 rows in flight per wave. Segmented reduce in LDS; flush means[e]:
// plain store if the segment lies fully inside this block's p-range,
// else global atomicAdd into the pre-zeroed means buffer.
// ---------------------------------------------------------------------------
__global__ __launch_bounds__(256) void means_kernel(
    const float* __restrict__ w_part,      // [BT][NPTS][NCH]
    const int*   __restrict__ sorted_idx,  // [BT][NPTS]
    const int*   __restrict__ segof,       // [BT][NPTS]
    const int4*  __restrict__ entries,     // [BT][NPTS]
    float*       __restrict__ means)       // [BT][NPTS][NCH] (zeroed)
{
    __shared__ float s_seg[257][CPAD];     // local segment accumulators

    const int tid = threadIdx.x;
    const int bt  = blockIdx.x >> 2;
    const int p0  = (blockIdx.x & 3) * 256;

    const int* __restrict__ sgo = segof + bt * NPTS;
    const int s0 = sgo[p0];
    const int s1 = sgo[p0 + 255];
    const int nseg = s1 - s0 + 1;          // <= 257

    float* flat = &s_seg[0][0];
    for (int i = tid; i < nseg * CPAD; i += 256) flat[i] = 0.0f;
    __syncthreads();

    const int pt    = tid >> 3;            // 0..31
    const int lane8 = tid & 7;             // 4 channels each
    const int* __restrict__ si = sorted_idx + bt * NPTS;
    const float* __restrict__ wp = w_part + (size_t)bt * NPTS * NCH;

#pragma unroll
    for (int pass = 0; pass < 8; ++pass) {
        const int p = p0 + pass * 32 + pt;
        const int j = si[p];
        const float4 v = *reinterpret_cast<const float4*>(
            wp + (size_t)j * NCH + lane8 * 4);
        float ss = v.x * v.x + v.y * v.y + v.z * v.z + v.w * v.w;
        ss += __shfl_xor(ss, 1);
        ss += __shfl_xor(ss, 2);
        ss += __shfl_xor(ss, 4);
        const float scale = 1.0f / fmaxf(sqrtf(ss), 1e-12f);
        const int ls = sgo[p] - s0;
        float* ap = &s_seg[ls][lane8 * 4];
        atomicAdd(ap + 0, v.x * scale);
        atomicAdd(ap + 1, v.y * scale);
        atomicAdd(ap + 2, v.z * scale);
        atomicAdd(ap + 3, v.w * scale);
    }
    __syncthreads();

    // ---- flush local segments to means ----
    const int grp = tid >> 5;              // 8 groups
    const int ch  = tid & 31;
    const int4* __restrict__ ent = entries + (size_t)bt * NPTS;
    for (int le = grp; le < nseg; le += 8) {
        const int e = s0 + le;
        const int4 meta = ent[e];          // {cell, cnt, start}... (cell,cnt,start)
        const int cnt   = meta.y;
        const int start = meta.z;
        const float val = s_seg[le][ch] * (1.0f / (float)cnt);
        float* dst = means + ((size_t)bt * NPTS + e) * NCH + ch;
        const bool owned = (start >= p0) && (start + cnt <= p0 + 256);
        if (owned) *dst = val;
        else       atomicAdd(dst, val);
    }
}

// ---------------------------------------------------------------------------
// Kernel C: gather-per-output-tile + fused combine. Per entry, entries[e] and
// means[bt][e] are BOTH directly indexed -> 1-deep chain, high MLP.
// ---------------------------------------------------------------------------
__global__ __launch_bounds__(TPB, 8) void tile_kernel(
    const float* __restrict__ means,         // [BT][NPTS][NCH]
    const int4*  __restrict__ entries,       // [BT][NPTS]
    const int*   __restrict__ ranges,        // [BT][CHUNKS+1]
    const float* __restrict__ past_w,        // [B][C][HW]
    const float* __restrict__ past_mask,     // [B][HW]
    float*       __restrict__ out_w,         // [B][C][HW]
    float*       __restrict__ out_mask)      // [B][HW]
{
    __shared__ float s_acc[CELLS][CPAD];
    __shared__ float s_mask[CELLS];

    const int tid   = threadIdx.x;
    const int b     = blockIdx.x & (BATCH - 1);   // XCD affinity
    const int chunk = blockIdx.x >> 3;
    const int cb    = chunk * CELLS;

    // ---- epilogue operand prefetch (issued first, overlaps gather) ----
    const int cellq = tid & 15;          // 4 consecutive cells
    const int cgrp  = tid >> 4;          // 0..15 -> 2 channels each
    const int c0    = cgrp * 2;
    const int gc    = cb + cellq * 4;
    const size_t mbase = (size_t)b * HW + gc;
    const float4 pm4 = *reinterpret_cast<const float4*>(past_mask + mbase);
    const size_t a0 = ((size_t)b * NCH + c0) * HW + gc;
    const float4 pw0 = *reinterpret_cast<const float4*>(past_w + a0);
    const float4 pw1 = *reinterpret_cast<const float4*>(past_w + a0 + HW);

    // ---- zero accumulators ----
    float* flat = &s_acc[0][0];
    for (int i = tid; i < CELLS * CPAD; i += TPB) flat[i] = 0.0f;
    if (tid < CELLS) s_mask[tid] = 0.0f;
    __syncthreads();

    // ---- gather phase: wave covers frames 2w, 2w+1 ----
    const int wave  = tid >> 6;          // 0..3
    const int lane  = tid & 63;
    const int slot  = lane >> 3;         // 8 entries in flight per wave
    const int lane8 = lane & 7;          // 4 channels each

#pragma unroll
    for (int tt = 0; tt < 2; ++tt) {
        const int t  = wave * 2 + tt;
        const int bt = b * TFRAMES + t;
        const int lo = ranges[bt * (CHUNKS + 1) + chunk];
        const int hi = ranges[bt * (CHUNKS + 1) + chunk + 1];
        const int4*  __restrict__ ent = entries + (size_t)bt * NPTS;
        const float* __restrict__ mns = means + (size_t)bt * NPTS * NCH;

        for (int e = lo + slot; e < hi; e += 8) {
            const int4 meta = ent[e];                 // direct in e
            const float4 mv = *reinterpret_cast<const float4*>(
                mns + (size_t)e * NCH + lane8 * 4);   // direct in e
            const int cl = meta.x - cb;
            float* ap = &s_acc[cl][lane8 * 4];
            atomicAdd(ap + 0, mv.x);
            atomicAdd(ap + 1, mv.y);
            atomicAdd(ap + 2, mv.z);
            atomicAdd(ap + 3, mv.w);
            if (lane8 == 0) atomicAdd(&s_mask[cl], (float)meta.y);
        }
    }
    __syncthreads();

    // ---- fused combine epilogue (register-prefetched operands) ----
    const float invT = 1.0f / (float)TFRAMES;
    float m[4], pm[4], r[4], dn[4];
    pm[0] = pm4.x; pm[1] = pm4.y; pm[2] = pm4.z; pm[3] = pm4.w;
#pragma unroll
    for (int i = 0; i < 4; ++i) {
        m[i] = s_mask[cellq * 4 + i];
        const float nwm = m[i] + pm[i];
        dn[i] = (nwm == 0.0f) ? 1.0f : nwm;
        r[i] = 1.0f / dn[i];
    }
    if (cgrp == 0) {
        *reinterpret_cast<float4*>(out_mask + mbase) =
            make_float4(dn[0], dn[1], dn[2], dn[3]);
    }

    float4 o0, o1;
    o0.x = (s_acc[cellq * 4 + 0][c0] * invT * m[0] + pw0.x * pm[0]) * r[0];
    o0.y = (s_acc[cellq * 4 + 1][c0] * invT * m[1] + pw0.y * pm[1]) * r[1];
    o0.z = (s_acc[cellq * 4 + 2][c0] * invT * m[2] + pw0.z * pm[2]) * r[2];
    o0.w = (s_acc[cellq * 4 + 3][c0] * invT * m[3] + pw0.w * pm[3]) * r[3];
    o1.x = (s_acc[cellq * 4 + 0][c0 + 1] * invT * m[0] + pw1.x * pm[0]) * r[0];
    o1.y = (s_acc[cellq * 4 + 1][c0 + 1] * invT * m[1] + pw1.y * pm[1]) * r[1];
    o1.z = (s_acc[cellq * 4 + 2][c0 + 1] * invT * m[2] + pw1.z * pm[2]) * r[2];
    o1.w = (s_acc[cellq * 4 + 3][c0 + 1] * invT * m[3] + pw1.w * pm[3]) * r[3];
    *reinterpret_cast<float4*>(out_w + a0)      = o0;
    *reinterpret_cast<float4*>(out_w + a0 + HW) = o1;
}

// ---------------------------------------------------------------------------
extern "C" void kernel_launch(void* const* d_in, const int* in_sizes, int n_in,
                              void* d_out, int out_size, void* d_ws, size_t ws_size,
                              hipStream_t stream) {
    (void)in_sizes; (void)n_in; (void)out_size; (void)ws_size;

    const float* w_part     = (const float*)d_in[0];
    const int*   sorted_idx = (const int*)d_in[1];
    const int*   uniq_list  = (const int*)d_in[2];
    const int*   uniq_cnt   = (const int*)d_in[3];
    const float* past_w     = (const float*)d_in[4];
    const float* past_mask  = (const float*)d_in[5];
    // d_in[6] is T (==TFRAMES), fixed constant.

    float* out      = (float*)d_out;
    float* out_w    = out;                                // [B][C][HW]
    float* out_mask = out + (size_t)BATCH * NCH * HW;     // [B][HW]

    // workspace layout
    int4*  entries = (int4*)d_ws;                         // 1 MB
    int*   ranges  = (int*)(entries + (size_t)BT * NPTS); // 64*257 ints
    int*   segof   = ranges + (size_t)BT * (CHUNKS + 1);  // 256 KB
    float* means   = (float*)(segof + (size_t)BT * NPTS); // 8 MB

    hipMemsetAsync(means, 0, (size_t)BT * NPTS * NCH * sizeof(float), stream);

    scan_kernel<<<BT, 256, 0, stream>>>(uniq_cnt, uniq_list, entries, ranges, segof);

    means_kernel<<<BT * 4, 256, 0, stream>>>(w_part, sorted_idx, segof, entries, means);

    tile_kernel<<<BATCH * CHUNKS, TPB, 0, stream>>>(
        means, entries, ranges, past_w, past_mask, out_w, out_mask);
}

// Round 8
// 29.616 us; speedup vs baseline: 2.1180x; 2.1180x over previous
//
#include <hip/hip_runtime.h>
#include <climits>

// Problem constants (fixed by the reference's setup_inputs()):
#define BATCH   8
#define TFRAMES 8
#define BT      (BATCH * TFRAMES)   // 64
#define NPTS    1024
#define NCH     32
#define WS      128
#define HW      (WS * WS)           // 16384
#define CELLS   128                 // cells per chunk
#define CHUNKS  (HW / CELLS)        // 128
#define CPAD    33                  // padded channel stride in LDS
#define TPB     512                 // 8 waves = 8 frames

// ---------------------------------------------------------------------------
// Kernel 0: per-frame scan -> self-contained entries + per-chunk {lo,hi}.
//   entries[bt][e] = { cell | (cnt<<16), j0, j1, start }
//     j0 = si[start], j1 = si[start+1] -> tile kernel needs NO sorted_idx hop
//     for cnt<=2 (99.9% of entries; lambda = 1024/16384 per cell).
//   ranges2[bt][k] = { first entry with key >= k*CELLS, same for k+1 }
// 64 blocks x 256 threads.
// ---------------------------------------------------------------------------
__global__ __launch_bounds__(256) void scan_kernel(
    const int* __restrict__ uniq_cnt,    // [BT][NPTS]
    const int* __restrict__ uniq_list,   // [BT][NPTS]
    const int* __restrict__ sorted_idx,  // [BT][NPTS]
    int4*      __restrict__ entries,     // [BT][NPTS]
    int2*      __restrict__ ranges2)     // [BT][CHUNKS]
{
    __shared__ int s_key[NPTS];
    __shared__ int s_wsum[4];
    __shared__ int s_bnd[CHUNKS + 1];

    const int tid  = threadIdx.x;
    const int bt   = blockIdx.x;
    const int wave = tid >> 6;
    const int lane = tid & 63;

    const int4 c4 = reinterpret_cast<const int4*>(uniq_cnt + bt * NPTS)[tid];
    const int4 l4 = reinterpret_cast<const int4*>(uniq_list + bt * NPTS)[tid];
    s_key[tid * 4 + 0] = (c4.x > 0) ? l4.x : INT_MAX;
    s_key[tid * 4 + 1] = (c4.y > 0) ? l4.y : INT_MAX;
    s_key[tid * 4 + 2] = (c4.z > 0) ? l4.z : INT_MAX;
    s_key[tid * 4 + 3] = (c4.w > 0) ? l4.w : INT_MAX;

    const int lsum = c4.x + c4.y + c4.z + c4.w;

    int inc = lsum;
#pragma unroll
    for (int d = 1; d < 64; d <<= 1) {
        const int v = __shfl_up(inc, d);
        if (lane >= d) inc += v;
    }
    if (lane == 63) s_wsum[wave] = inc;
    __syncthreads();

    int woff = 0;
#pragma unroll
    for (int w = 0; w < 4; ++w)
        if (w < wave) woff += s_wsum[w];

    const int* __restrict__ si = sorted_idx + bt * NPTS;
    int st = woff + inc - lsum;   // exclusive prefix for this thread's 4 slots
    int4* ep = entries + (size_t)bt * NPTS + tid * 4;

    const int cc[4] = {c4.x, c4.y, c4.z, c4.w};
    const int ll[4] = {l4.x, l4.y, l4.z, l4.w};
#pragma unroll
    for (int k = 0; k < 4; ++k) {
        const int cnt = cc[k];
        const int j0  = (cnt > 0) ? si[st]     : 0;
        const int j1  = (cnt > 1) ? si[st + 1] : 0;
        ep[k] = make_int4(ll[k] | (cnt << 16), j0, j1, st);
        st += cnt;
    }

    // per-chunk boundary searches over LDS keys
    if (tid <= CHUNKS) {
        const int X = tid * CELLS;
        int lo = 0, hi = NPTS;
        while (lo < hi) {
            const int mid = (lo + hi) >> 1;
            if (s_key[mid] < X) lo = mid + 1; else hi = mid;
        }
        s_bnd[tid] = lo;
    }
    __syncthreads();
    if (tid < CHUNKS)
        ranges2[bt * CHUNKS + tid] = make_int2(s_bnd[tid], s_bnd[tid + 1]);
}

// ---------------------------------------------------------------------------
// Kernel 1: gather-per-output-tile + fused combine.
// Block = (batch b, chunk of 128 cells); 8 waves, ONE frame per wave.
// Chain is ranges2 -> entry -> w_row (3-deep), and the first TWO entry
// rounds (16 entries; covers 99.8% of chunk-frames, lambda~7.8) are issued
// BEFORE __syncthreads so their latency hides under LDS zeroing.
// Grid 1024 blocks x 8 waves = exactly resident at 8 waves/SIMD.
// ---------------------------------------------------------------------------
__global__ __launch_bounds__(TPB, 8) void tile_kernel(
    const float* __restrict__ w_part,        // [BT][NPTS][NCH]
    const int*   __restrict__ sorted_idx,    // [BT][NPTS]
    const int4*  __restrict__ entries,       // [BT][NPTS]
    const int2*  __restrict__ ranges2,       // [BT][CHUNKS]
    const float* __restrict__ past_w,        // [B][C][HW]
    const float* __restrict__ past_mask,     // [B][HW]
    float*       __restrict__ out_w,         // [B][C][HW]
    float*       __restrict__ out_mask)      // [B][HW]
{
    __shared__ float s_acc[CELLS][CPAD];
    __shared__ float s_mask[CELLS];

    const int tid   = threadIdx.x;
    const int b     = blockIdx.x & (BATCH - 1);   // XCD affinity
    const int chunk = blockIdx.x >> 3;
    const int cb    = chunk * CELLS;

    // ---- epilogue operand prefetch (independent; issued first) ----
    const int cellq = tid & 31;          // 4 consecutive cells
    const int cgrp  = tid >> 5;          // 0..15 -> 2 channels each
    const int c0    = cgrp * 2;
    const int gc    = cb + cellq * 4;
    const size_t mbase = (size_t)b * HW + gc;
    const float4 pm4 = *reinterpret_cast<const float4*>(past_mask + mbase);
    const size_t a0 = ((size_t)b * NCH + c0) * HW + gc;
    const float4 pw0 = *reinterpret_cast<const float4*>(past_w + a0);
    const float4 pw1 = *reinterpret_cast<const float4*>(past_w + a0 + HW);

    // ---- gather-phase prefetch (issued before the barrier) ----
    const int wave  = tid >> 6;          // 0..7 == frame t
    const int lane  = tid & 63;
    const int slot  = lane >> 3;         // 8 entries in flight per round
    const int lane8 = lane & 7;          // 4 channels each

    const int bt = b * TFRAMES + wave;
    const int2 rg = ranges2[bt * CHUNKS + chunk];
    const int lo = rg.x, hi = rg.y;

    const int4* __restrict__ ent = entries + (size_t)bt * NPTS;
    const float* __restrict__ wp = w_part + (size_t)bt * NPTS * NCH;

    const int eA = lo + slot;
    const int eB = eA + 8;
    const bool vA = (eA < hi);
    const bool vB = (eB < hi);
    const int4 metaA = ent[vA ? eA : 0];
    const int4 metaB = ent[vB ? eB : 0];
    const float4 vwA = *reinterpret_cast<const float4*>(
        wp + (size_t)metaA.y * NCH + lane8 * 4);
    const float4 vwB = *reinterpret_cast<const float4*>(
        wp + (size_t)metaB.y * NCH + lane8 * 4);

    // ---- zero accumulators (overlaps the in-flight loads above) ----
    float* flat = &s_acc[0][0];
    for (int i = tid; i < CELLS * CPAD; i += TPB) flat[i] = 0.0f;
    if (tid < CELLS) s_mask[tid] = 0.0f;
    __syncthreads();

    // ---- process an entry given its meta and prefetched first row ----
    const int* __restrict__ si = sorted_idx + bt * NPTS;
    auto process = [&](const int4 meta, const float4 v0) {
        const int cell  = meta.x & 0xFFFF;
        const int cnt   = meta.x >> 16;
        float ss = v0.x * v0.x + v0.y * v0.y + v0.z * v0.z + v0.w * v0.w;
        ss += __shfl_xor(ss, 1);
        ss += __shfl_xor(ss, 2);
        ss += __shfl_xor(ss, 4);
        const float s0 = 1.0f / fmaxf(sqrtf(ss), 1e-12f);
        float4 lacc = make_float4(v0.x * s0, v0.y * s0, v0.z * s0, v0.w * s0);
        if (cnt > 1) {
            const float4 v1 = *reinterpret_cast<const float4*>(
                wp + (size_t)meta.z * NCH + lane8 * 4);
            float s1 = v1.x * v1.x + v1.y * v1.y + v1.z * v1.z + v1.w * v1.w;
            s1 += __shfl_xor(s1, 1);
            s1 += __shfl_xor(s1, 2);
            s1 += __shfl_xor(s1, 4);
            s1 = 1.0f / fmaxf(sqrtf(s1), 1e-12f);
            lacc.x += v1.x * s1; lacc.y += v1.y * s1;
            lacc.z += v1.z * s1; lacc.w += v1.w * s1;
            for (int p = meta.w + 2; p < meta.w + cnt; ++p) {   // rare
                const int j = si[p];
                const float4 v = *reinterpret_cast<const float4*>(
                    wp + (size_t)j * NCH + lane8 * 4);
                float sv = v.x * v.x + v.y * v.y + v.z * v.z + v.w * v.w;
                sv += __shfl_xor(sv, 1);
                sv += __shfl_xor(sv, 2);
                sv += __shfl_xor(sv, 4);
                sv = 1.0f / fmaxf(sqrtf(sv), 1e-12f);
                lacc.x += v.x * sv; lacc.y += v.y * sv;
                lacc.z += v.z * sv; lacc.w += v.w * sv;
            }
        }
        const float invc = 1.0f / (float)cnt;
        const int cl = cell - cb;
        float* ap = &s_acc[cl][lane8 * 4];
        atomicAdd(ap + 0, lacc.x * invc);
        atomicAdd(ap + 1, lacc.y * invc);
        atomicAdd(ap + 2, lacc.z * invc);
        atomicAdd(ap + 3, lacc.w * invc);
        if (lane8 == 0) atomicAdd(&s_mask[cl], (float)cnt);
    };

    if (vA) process(metaA, vwA);
    if (vB) process(metaB, vwB);
    for (int e = lo + 16 + slot; e < hi; e += 8) {      // rare 3rd+ rounds
        const int4 meta = ent[e];
        const float4 v0 = *reinterpret_cast<const float4*>(
            wp + (size_t)meta.y * NCH + lane8 * 4);
        process(meta, v0);
    }
    __syncthreads();

    // ---- fused combine epilogue (register-prefetched operands) ----
    const float invT = 1.0f / (float)TFRAMES;
    float m[4], pm[4], r[4], dn[4];
    pm[0] = pm4.x; pm[1] = pm4.y; pm[2] = pm4.z; pm[3] = pm4.w;
#pragma unroll
    for (int i = 0; i < 4; ++i) {
        m[i] = s_mask[cellq * 4 + i];
        const float nwm = m[i] + pm[i];
        dn[i] = (nwm == 0.0f) ? 1.0f : nwm;
        r[i] = 1.0f / dn[i];
    }
    if (cgrp == 0) {
        *reinterpret_cast<float4*>(out_mask + mbase) =
            make_float4(dn[0], dn[1], dn[2], dn[3]);
    }

    float4 o0, o1;
    o0.x = (s_acc[cellq * 4 + 0][c0] * invT * m[0] + pw0.x * pm[0]) * r[0];
    o0.y = (s_acc[cellq * 4 + 1][c0] * invT * m[1] + pw0.y * pm[1]) * r[1];
    o0.z = (s_acc[cellq * 4 + 2][c0] * invT * m[2] + pw0.z * pm[2]) * r[2];
    o0.w = (s_acc[cellq * 4 + 3][c0] * invT * m[3] + pw0.w * pm[3]) * r[3];
    o1.x = (s_acc[cellq * 4 + 0][c0 + 1] * invT * m[0] + pw1.x * pm[0]) * r[0];
    o1.y = (s_acc[cellq * 4 + 1][c0 + 1] * invT * m[1] + pw1.y * pm[1]) * r[1];
    o1.z = (s_acc[cellq * 4 + 2][c0 + 1] * invT * m[2] + pw1.z * pm[2]) * r[2];
    o1.w = (s_acc[cellq * 4 + 3][c0 + 1] * invT * m[3] + pw1.w * pm[3]) * r[3];
    *reinterpret_cast<float4*>(out_w + a0)      = o0;
    *reinterpret_cast<float4*>(out_w + a0 + HW) = o1;
}

// ---------------------------------------------------------------------------
extern "C" void kernel_launch(void* const* d_in, const int* in_sizes, int n_in,
                              void* d_out, int out_size, void* d_ws, size_t ws_size,
                              hipStream_t stream) {
    (void)in_sizes; (void)n_in; (void)out_size; (void)ws_size;

    const float* w_part     = (const float*)d_in[0];
    const int*   sorted_idx = (const int*)d_in[1];
    const int*   uniq_list  = (const int*)d_in[2];
    const int*   uniq_cnt   = (const int*)d_in[3];
    const float* past_w     = (const float*)d_in[4];
    const float* past_mask  = (const float*)d_in[5];
    // d_in[6] is T (==TFRAMES), fixed constant.

    float* out      = (float*)d_out;
    float* out_w    = out;                                // [B][C][HW]
    float* out_mask = out + (size_t)BATCH * NCH * HW;     // [B][HW]

    int4* entries = (int4*)d_ws;                          // [BT][NPTS] 1 MB
    int2* ranges2 = (int2*)(entries + (size_t)BT * NPTS); // [BT][CHUNKS] 64 KB

    scan_kernel<<<BT, 256, 0, stream>>>(uniq_cnt, uniq_list, sorted_idx,
                                        entries, ranges2);

    tile_kernel<<<BATCH * CHUNKS, TPB, 0, stream>>>(
        w_part, sorted_idx, entries, ranges2,
        past_w, past_mask, out_w, out_mask);
}